// Round 9
// baseline (223.818 us; speedup 1.0000x reference)
//
#include <hip/hip_runtime.h>
#include <math.h>

typedef _Float16 f16x8 __attribute__((ext_vector_type(8)));
typedef float    f32x16 __attribute__((ext_vector_type(16)));

constexpr int D_DIM = 2048;
constexpr int N_EXP = 64;
constexpr int BM    = 32;        // rows per block
constexpr int KW    = 512;       // K-range per wave (D/4)
constexpr int KC    = 32;        // K per chunk (2 MFMA k-steps)
constexpr int NCH   = KW / KC;   // 16

// ---- pre-pass: W fp32 -> split fp16 pair (W = W1 + W2/2048), once per call ----
__global__ __launch_bounds__(256) void split_w_kernel(
    const float* __restrict__ W, _Float16* __restrict__ W1, _Float16* __restrict__ W2)
{
    const int i = (blockIdx.x * 256 + threadIdx.x) * 8;
    const float4 a = *(const float4*)(W + i);
    const float4 b = *(const float4*)(W + i + 4);
    const float v[8] = {a.x, a.y, a.z, a.w, b.x, b.y, b.z, b.w};
    f16x8 h1, h2;
#pragma unroll
    for (int j = 0; j < 8; ++j) {
        const _Float16 p = (_Float16)v[j];
        h1[j] = p;
        h2[j] = (_Float16)((v[j] - (float)p) * 2048.f);
    }
    *(f16x8*)(W1 + i) = h1;
    *(f16x8*)(W2 + i) = h2;
}

__device__ inline void split8(const float4& a, const float4& b, f16x8& h1, f16x8& h2)
{
    const float v[8] = {a.x, a.y, a.z, a.w, b.x, b.y, b.z, b.w};
#pragma unroll
    for (int j = 0; j < 8; ++j) {
        const _Float16 p = (_Float16)v[j];
        h1[j] = p;
        h2[j] = (_Float16)((v[j] - (float)p) * 2048.f);
    }
}

// 256 threads = 4 waves; waves split K (512 each). LDS-free main loop: x and
// split-W fragments are loaded per-lane directly in MFMA fragment layout
// (lane&31 = row, k = (lane>>5)*8+j, 8 contiguous elems). Depth-2 register
// double-buffer; chunk loop fully unrolled so buffer indices are static.
__global__ __launch_bounds__(256, 2) void topk_router_kernel(
    const float* __restrict__ x, const _Float16* __restrict__ W1,
    const _Float16* __restrict__ W2,
    float* __restrict__ outProbs, float* __restrict__ outIdx,
    float* __restrict__ outWt)
{
    __shared__ __align__(16) float scratch[4][BM * 68];   // 34,816 B

    const int t    = threadIdx.x;
    const int lane = t & 63;
    const int wave = t >> 6;
    const int rowBase = blockIdx.x * BM;

    const int fr = lane & 31;          // fragment row (x row / W expert)
    const int fh = (lane >> 5) * 8;    // k sub-offset within k-step

    const int k0 = wave * KW;
    const float*    xp  = x  + (size_t)(rowBase + fr) * D_DIM + k0 + fh;
    const _Float16* w1a = W1 + (size_t)fr        * D_DIM + k0 + fh;   // experts 0..31
    const _Float16* w1b = W1 + (size_t)(32 + fr) * D_DIM + k0 + fh;   // experts 32..63
    const _Float16* w2a = W2 + (size_t)fr        * D_DIM + k0 + fh;
    const _Float16* w2b = W2 + (size_t)(32 + fr) * D_DIM + k0 + fh;

    float4 xA[2][4];        // [buf][ks*2 + half]
    f16x8  wA[2][8];        // [buf][ks*4 + {W1a,W2a,W1b,W2b}]

#define LOADC(b, ch) do {                                   \
        const int kb_ = (ch) * KC;                          \
        xA[b][0] = *(const float4*)(xp + kb_);              \
        xA[b][1] = *(const float4*)(xp + kb_ + 4);          \
        xA[b][2] = *(const float4*)(xp + kb_ + 16);         \
        xA[b][3] = *(const float4*)(xp + kb_ + 20);         \
        wA[b][0] = *(const f16x8*)(w1a + kb_);              \
        wA[b][1] = *(const f16x8*)(w2a + kb_);              \
        wA[b][2] = *(const f16x8*)(w1b + kb_);              \
        wA[b][3] = *(const f16x8*)(w2b + kb_);              \
        wA[b][4] = *(const f16x8*)(w1a + kb_ + 16);         \
        wA[b][5] = *(const f16x8*)(w2a + kb_ + 16);         \
        wA[b][6] = *(const f16x8*)(w1b + kb_ + 16);         \
        wA[b][7] = *(const f16x8*)(w2b + kb_ + 16);         \
    } while (0)

    f32x16 acc0[2], acc1[2];
#pragma unroll
    for (int n = 0; n < 2; ++n)
#pragma unroll
        for (int i = 0; i < 16; ++i) { acc0[n][i] = 0.f; acc1[n][i] = 0.f; }

    LOADC(0, 0);
    LOADC(1, 1);

#pragma unroll
    for (int ch = 0; ch < NCH; ++ch) {
        const int b = ch & 1;
#pragma unroll
        for (int ks = 0; ks < 2; ++ks) {
            f16x8 A1, A2;
            split8(xA[b][ks * 2], xA[b][ks * 2 + 1], A1, A2);
            const f16x8 B1a = wA[b][ks * 4 + 0];
            const f16x8 B2a = wA[b][ks * 4 + 1];
            const f16x8 B1b = wA[b][ks * 4 + 2];
            const f16x8 B2b = wA[b][ks * 4 + 3];
            acc0[0] = __builtin_amdgcn_mfma_f32_32x32x16_f16(A1, B1a, acc0[0], 0, 0, 0);
            acc1[0] = __builtin_amdgcn_mfma_f32_32x32x16_f16(A1, B2a, acc1[0], 0, 0, 0);
            acc1[0] = __builtin_amdgcn_mfma_f32_32x32x16_f16(A2, B1a, acc1[0], 0, 0, 0);
            acc0[1] = __builtin_amdgcn_mfma_f32_32x32x16_f16(A1, B1b, acc0[1], 0, 0, 0);
            acc1[1] = __builtin_amdgcn_mfma_f32_32x32x16_f16(A1, B2b, acc1[1], 0, 0, 0);
            acc1[1] = __builtin_amdgcn_mfma_f32_32x32x16_f16(A2, B1b, acc1[1], 0, 0, 0);
        }
        if (ch + 2 < NCH) LOADC(b, ch + 2);
    }
#undef LOADC

    // ---- per-wave partials -> scratch (verified C layout) ----
    float* scr = scratch[wave];
    const float S2 = 1.0f / 2048.0f;
#pragma unroll
    for (int n = 0; n < 2; ++n)
#pragma unroll
        for (int rg = 0; rg < 16; ++rg) {
            const int row = (rg & 3) + 8 * (rg >> 2) + 4 * (lane >> 5);
            const int col = n * 32 + fr;
            scr[row * 68 + col] = acc0[n][rg] + acc1[n][rg] * S2;
        }
    __syncthreads();

    // ---- deterministic 4-way reduce: thread t -> row t>>3, experts (t&7)*8.. ----
    const int r  = t >> 3;
    const int e0 = (t & 7) * 8;
    float lg[8];
#pragma unroll
    for (int j = 0; j < 8; ++j) lg[j] = 0.f;
#pragma unroll
    for (int w = 0; w < 4; ++w) {
        const float* s = scratch[w] + r * 68 + e0;
        const float4 a = *(const float4*)s;
        const float4 b = *(const float4*)(s + 4);
        lg[0] += a.x; lg[1] += a.y; lg[2] += a.z; lg[3] += a.w;
        lg[4] += b.x; lg[5] += b.y; lg[6] += b.z; lg[7] += b.w;
    }

    // local top-2 (ascending j => lower index wins ties)
    float v1 = lg[0]; int i1 = e0; float v2 = -INFINITY; int i2 = 0;
#pragma unroll
    for (int j = 1; j < 8; ++j) {
        const float v = lg[j]; const int id = e0 + j;
        if (v > v1)      { v2 = v1; i2 = i1; v1 = v; i1 = id; }
        else if (v > v2) { v2 = v;  i2 = id; }
    }
    // butterfly merge across the 8 lanes sharing this row
#pragma unroll
    for (int m = 1; m < 8; m <<= 1) {
        const float ov1 = __shfl_xor(v1, m, 64); const int oi1 = __shfl_xor(i1, m, 64);
        const float ov2 = __shfl_xor(v2, m, 64); const int oi2 = __shfl_xor(i2, m, 64);
        float n1, n2; int ni1, ni2;
        const bool o1_wins = (ov1 > v1) || (ov1 == v1 && oi1 < i1);
        if (o1_wins) {
            n1 = ov1; ni1 = oi1;
            const bool a1_beats_o2 = (v1 > ov2) || (v1 == ov2 && i1 < oi2);
            if (a1_beats_o2) { n2 = v1;  ni2 = i1;  } else { n2 = ov2; ni2 = oi2; }
        } else {
            n1 = v1; ni1 = i1;
            const bool o1_beats_a2 = (ov1 > v2) || (ov1 == v2 && oi1 < i2);
            if (o1_beats_a2) { n2 = ov1; ni2 = oi1; } else { n2 = v2;  ni2 = i2;  }
        }
        v1 = n1; i1 = ni1; v2 = n2; i2 = ni2;
    }

    // softmax
    float ee[8]; float S = 0.f;
#pragma unroll
    for (int j = 0; j < 8; ++j) { ee[j] = __expf(lg[j] - v1); S += ee[j]; }
    S += __shfl_xor(S, 1, 64);
    S += __shfl_xor(S, 2, 64);
    S += __shfl_xor(S, 4, 64);
    const float rS = 1.0f / S;

    const int row = rowBase + r;
    float4 pa = {ee[0] * rS, ee[1] * rS, ee[2] * rS, ee[3] * rS};
    float4 pb = {ee[4] * rS, ee[5] * rS, ee[6] * rS, ee[7] * rS};
    *(float4*)(outProbs + (size_t)row * N_EXP + e0)     = pa;
    *(float4*)(outProbs + (size_t)row * N_EXP + e0 + 4) = pb;

    if ((t & 7) == 0) {
        const float p1 = rS;                      // exp(v1-v1)*rS
        const float p2 = __expf(v2 - v1) * rS;
        const float den = p1 + p2 + 1e-9f;
        outIdx[row * 2 + 0] = (float)i1;
        outIdx[row * 2 + 1] = (float)i2;
        outWt [row * 2 + 0] = p1 / den;
        outWt [row * 2 + 1] = p2 / den;
    }
}

extern "C" void kernel_launch(void* const* d_in, const int* in_sizes, int n_in,
                              void* d_out, int out_size, void* d_ws, size_t ws_size,
                              hipStream_t stream) {
    const float* x = (const float*)d_in[0];
    const float* W = (const float*)d_in[1];
    const int nRows = in_sizes[0] / D_DIM;               // 16384

    float* outProbs = (float*)d_out;                     // nRows*64
    float* outIdx   = outProbs + (size_t)nRows * N_EXP;  // nRows*2 (float-cast ints)
    float* outWt    = outIdx   + (size_t)nRows * 2;      // nRows*2

    _Float16* W1h = (_Float16*)d_ws;                     // 64*2048 fp16
    _Float16* W2h = W1h + (size_t)N_EXP * D_DIM;         // 64*2048 fp16 (512 KB total)

    split_w_kernel<<<dim3(64), dim3(256), 0, stream>>>(W, W1h, W2h);
    topk_router_kernel<<<dim3(nRows / BM), dim3(256), 0, stream>>>(
        x, W1h, W2h, outProbs, outIdx, outWt);
}